// Round 1
// baseline (528.917 us; speedup 1.0000x reference)
//
#include <hip/hip_runtime.h>

#define NUM_USER 60000
#define NUM_ITEM 40000
#define NN 100000
#define NE 500000
#define DIM 64
#define KF 4
#define SCAN_CHUNK 512
#define NBLK_SCAN ((NN + 1 + SCAN_CHUNK - 1) / SCAN_CHUNK)
// padded slot-count upper bounds (each node rounds up to multiple of 4)
#define NEPU_MAX (NE + 3 * NUM_USER)   // 680000 user-side slots max
#define NEPI_MAX (NE + 3 * NUM_ITEM)   // 620000 item-side slots max

// sum within each 16-lane group (butterfly: all lanes get result)
__device__ __forceinline__ float red16(float v) {
    v += __shfl_xor(v, 1);
    v += __shfl_xor(v, 2);
    v += __shfl_xor(v, 4);
    v += __shfl_xor(v, 8);
    return v;
}

__device__ __forceinline__ float b2f(unsigned short u) {
    return __uint_as_float(((unsigned)u) << 16);
}
__device__ __forceinline__ unsigned short f2b(float x) {
    unsigned u = __float_as_uint(x);
    u = (u + 0x7fffu + ((u >> 16) & 1u)) >> 16;   // RNE
    return (unsigned short)u;
}
// combined item word: high16 = T (bf16 bits), low16 = ego (bf16 bits)
__device__ __forceinline__ float cvt_lo(unsigned c) { return __uint_as_float(c << 16); }
__device__ __forceinline__ float cvt_hi(unsigned c) { return __uint_as_float(c & 0xffff0000u); }

__device__ __forceinline__ float4 softmax4(float4 s) {
    float m = fmaxf(fmaxf(s.x, s.y), fmaxf(s.z, s.w));
    float e0 = expf(s.x - m), e1 = expf(s.y - m), e2 = expf(s.z - m), e3 = expf(s.w - m);
    float inv = 1.0f / (e0 + e1 + e2 + e3);
    return make_float4(e0 * inv, e1 * inv, e2 * inv, e3 * inv);
}

// wave per node. Users: egoU(bf16) + allemb. Items: cmbI = (tanh(l2n16)<<16)|ego.
__global__ void k_init(const float* __restrict__ user, const float* __restrict__ item,
                       unsigned short* __restrict__ egoU, unsigned* __restrict__ cmbI,
                       float* __restrict__ allemb) {
    int node = (blockIdx.x * blockDim.x + threadIdx.x) >> 6;
    int lane = threadIdx.x & 63;
    if (node >= NN) return;
    int i = node * DIM + lane;
    if (node < NUM_USER) {
        float v = user[i];
        egoU[i] = f2b(v);
        allemb[i] = v;
    } else {
        float v = item[i - NUM_USER * DIM];
        allemb[i] = v;
        float ss = red16(v * v);
        float t = tanhf(v / fmaxf(sqrtf(ss), 1e-12f));
        cmbI[i - NUM_USER * DIM] = (((unsigned)f2b(t)) << 16) | (unsigned)f2b(v);
    }
}

__global__ void k_count(const int* __restrict__ row0, const int* __restrict__ col0,
                        int* __restrict__ cnt) {
    int e = blockIdx.x * blockDim.x + threadIdx.x;
    if (e >= NE) return;
    atomicAdd(&cnt[row0[e]], 1);
    atomicAdd(&cnt[col0[e]], 1);
}

// dinv + padded counts (round degree up to multiple of 4)
__global__ void k_dinv_pad(const int* __restrict__ cnt, float* __restrict__ dinv,
                           int* __restrict__ cntp) {
    int i = blockIdx.x * blockDim.x + threadIdx.x;
    if (i >= NN) return;
    int d = cnt[i];
    dinv[i] = (d > 0) ? rsqrtf((float)d) : 0.0f;
    cntp[i] = (d + 3) & ~3;
}

// --- 3-stage exclusive scan over cntp[NN] -> ptr[NN+1] ---
__global__ void k_scan1(const int* __restrict__ cnt, int* __restrict__ ptr,
                        int* __restrict__ bsum) {
    __shared__ int sm[SCAN_CHUNK];
    int tid = threadIdx.x;
    int idx = blockIdx.x * SCAN_CHUNK + tid;
    int x = (idx < NN) ? cnt[idx] : 0;
    sm[tid] = x;
    __syncthreads();
    for (int off = 1; off < SCAN_CHUNK; off <<= 1) {
        int v = (tid >= off) ? sm[tid - off] : 0;
        __syncthreads();
        sm[tid] += v;
        __syncthreads();
    }
    if (idx <= NN) ptr[idx] = sm[tid] - x;
    if (tid == SCAN_CHUNK - 1) bsum[blockIdx.x] = sm[tid];
}

__global__ void k_scan2(int* __restrict__ bsum, int* __restrict__ offs) {
    __shared__ int sm[256];
    int tid = threadIdx.x;
    int x = (tid < NBLK_SCAN) ? bsum[tid] : 0;
    sm[tid] = x;
    __syncthreads();
    for (int off = 1; off < 256; off <<= 1) {
        int v = (tid >= off) ? sm[tid - off] : 0;
        __syncthreads();
        sm[tid] += v;
        __syncthreads();
    }
    if (tid < NBLK_SCAN) offs[tid] = sm[tid] - x;
}

__global__ void k_scan3(int* __restrict__ ptr, const int* __restrict__ offs) {
    int idx = blockIdx.x * blockDim.x + threadIdx.x;
    if (idx <= NN) ptr[idx] += offs[idx / SCAN_CHUNK];
}

// fill CSR. user-side slots are [0, ptr[NUM_USER]); src stored ITEM-LOCAL there.
// jit[user_slot] = item-local slot of the same edge (for witem scatter in supd).
__global__ void k_fill(const int* __restrict__ row0, const int* __restrict__ col0,
                       int* __restrict__ pos, const int* __restrict__ ptr,
                       int* __restrict__ srcadj, int* __restrict__ jit,
                       int* __restrict__ jpos1) {
    int e = blockIdx.x * blockDim.x + threadIdx.x;
    if (e >= NE) return;
    int r = row0[e], c = col0[e];
    int ptrU = ptr[NUM_USER];
    int j1 = atomicAdd(&pos[r], 1);   // user-side slot: dst=r, src=c (item-local)
    srcadj[j1] = c - NUM_USER;
    jpos1[e] = j1;
    int j0 = atomicAdd(&pos[c], 1);   // item-side slot: dst=c, src=r
    srcadj[j0] = r;
    jit[j1] = j0 - ptrU;
}

// fill dummy (padding) slots: src=0 (weight is 0 so value harmless)
__global__ void k_pad(const int* __restrict__ cnt, const int* __restrict__ ptr,
                      int* __restrict__ srcadj) {
    int n = blockIdx.x * blockDim.x + threadIdx.x;
    if (n >= NN) return;
    int realend = ptr[n] + cnt[n];
    int end = ptr[n + 1];
    for (int j = realend; j < end; ++j) srcadj[j] = 0;
}

// permute S into slot order, norm per slot, initial weights in BOTH orderings
// (real slots only; dummy slots stay 0 from the memsets)
__global__ void k_w0(const float* __restrict__ Sin, const int* __restrict__ row0,
                     const int* __restrict__ col0, const int* __restrict__ jpos1,
                     const int* __restrict__ jit, const float* __restrict__ dinv,
                     float4* __restrict__ Scur4, float* __restrict__ normu,
                     float4* __restrict__ wuser, float4* __restrict__ witem) {
    int e = blockIdx.x * blockDim.x + threadIdx.x;
    if (e >= NE) return;
    int j = jpos1[e];
    float n = dinv[row0[e]] * dinv[col0[e]];
    float4 s = make_float4(Sin[e], Sin[NE + e], Sin[2 * NE + e], Sin[3 * NE + e]);
    float4 p = softmax4(s);
    Scur4[j] = s;
    normu[j] = n;
    float4 w = make_float4(n * p.x, n * p.y, n * p.z, n * p.w);
    wuser[j] = w;
    witem[jit[j]] = w;
}

// Scur4 (slot order) -> Sout [4][E] original edge order
__global__ void k_sout(const float4* __restrict__ Scur4, const int* __restrict__ jpos1,
                       float* __restrict__ Sout) {
    int e = blockIdx.x * blockDim.x + threadIdx.x;
    if (e >= NE) return;
    float4 s = Scur4[jpos1[e]];
    Sout[e] = s.x;
    Sout[NE + e] = s.y;
    Sout[2 * NE + e] = s.z;
    Sout[3 * NE + e] = s.w;
}

// fused gather conv + routing score. wave per node; branch-free x4 loops
// (degree padded to multiple of 4). lane = dim, k = lane>>4 = factor.
// Users gather cmbI rows (ego low16); score pass re-reads SAME lines for T (L1 hot).
// Items gather egoU rows; weights read sequentially from witem (no eitem gather).
// flags: 1 = layer end (allemb += acc), 4 = write next ego (items: +tanh T)
__global__ __launch_bounds__(256) void k_conv_score(
        const int* __restrict__ ptr, const int* __restrict__ srcadj,
        const float* __restrict__ wuser, const float* __restrict__ witem,
        float* __restrict__ pscore, const unsigned short* __restrict__ egoU,
        const unsigned* __restrict__ cmbI, unsigned short* __restrict__ xnextU,
        unsigned* __restrict__ cmbNext, float* __restrict__ allemb, int flags) {
    int node = (blockIdx.x * blockDim.x + threadIdx.x) >> 6;
    int lane = threadIdx.x & 63;
    if (node >= NN) return;
    int beg = __builtin_amdgcn_readfirstlane(ptr[node]);
    int end = __builtin_amdgcn_readfirstlane(ptr[node + 1]);
    int k = lane >> 4;

    float a0 = 0.0f, a1 = 0.0f, a2 = 0.0f, a3 = 0.0f;

    if (node >= NUM_USER) {
        // ---- item side: conv only ----
        int ptrU = __builtin_amdgcn_readfirstlane(ptr[NUM_USER]);
        const float* wI = witem + (size_t)4 * (beg - ptrU);
        int nslot = end - beg;
        for (int t = 0; t < nslot; t += 4) {
            int4 s = *(const int4*)(srcadj + beg + t);
            float w0 = wI[4 * t + k], w1 = wI[4 * t + 4 + k];
            float w2 = wI[4 * t + 8 + k], w3 = wI[4 * t + 12 + k];
            a0 = fmaf(w0, b2f(egoU[s.x * DIM + lane]), a0);
            a1 = fmaf(w1, b2f(egoU[s.y * DIM + lane]), a1);
            a2 = fmaf(w2, b2f(egoU[s.z * DIM + lane]), a2);
            a3 = fmaf(w3, b2f(egoU[s.w * DIM + lane]), a3);
        }
        float acc = (a0 + a1) + (a2 + a3);
        if (flags & 1) {
            int i = node * DIM + lane;
            allemb[i] += acc;
            if (flags & 4) {
                float ss = red16(acc * acc);
                float t = tanhf(acc / fmaxf(sqrtf(ss), 1e-12f));
                cmbNext[i - NUM_USER * DIM] =
                    (((unsigned)f2b(t)) << 16) | (unsigned)f2b(acc);
            }
        }
        return;
    }

    // ---- user side: conv + routing score ----
    for (int j = beg; j < end; j += 4) {
        int4 s = *(const int4*)(srcadj + j);
        float w0 = wuser[4 * j + k], w1 = wuser[4 * j + 4 + k];
        float w2 = wuser[4 * j + 8 + k], w3 = wuser[4 * j + 12 + k];
        a0 = fmaf(w0, cvt_lo(cmbI[s.x * DIM + lane]), a0);
        a1 = fmaf(w1, cvt_lo(cmbI[s.y * DIM + lane]), a1);
        a2 = fmaf(w2, cvt_lo(cmbI[s.z * DIM + lane]), a2);
        a3 = fmaf(w3, cvt_lo(cmbI[s.w * DIM + lane]), a3);
    }
    float acc = (a0 + a1) + (a2 + a3);

    if (flags & 1) {
        int i = node * DIM + lane;
        allemb[i] += acc;
        if (flags & 4) xnextU[i] = f2b(acc);
    }

    // routing score: pscore[4*j+k] = <u, T[src_j]>_16. Same cmbI lines as loop 1
    // (high halves), so these gathers are L1/L2-hot.
    float ssu = red16(acc * acc);
    float u = acc / fmaxf(sqrtf(ssu), 1e-12f);
    bool lead = (lane & 15) == 0;
    for (int j = beg; j < end; j += 4) {
        int4 s = *(const int4*)(srcadj + j);
        float p0 = red16(u * cvt_hi(cmbI[s.x * DIM + lane]));
        float p1 = red16(u * cvt_hi(cmbI[s.y * DIM + lane]));
        float p2 = red16(u * cvt_hi(cmbI[s.z * DIM + lane]));
        float p3 = red16(u * cvt_hi(cmbI[s.w * DIM + lane]));
        if (lead) {
            pscore[4 * j + k] = p0;
            pscore[4 * j + 4 + k] = p1;
            pscore[4 * j + 8 + k] = p2;
            pscore[4 * j + 12 + k] = p3;
        }
    }
}

// thread per padded user slot: snew = softmax4(S4)+pscore; S4=snew;
// if !last: w = normu * softmax4(snew), written in user order + scattered to
// item order (dummy slots: normu=0 -> w=0, no scatter)
__global__ void k_supd(const int* __restrict__ ptr, float4* __restrict__ S4,
                       const float4* __restrict__ pscore, const float* __restrict__ normu,
                       const int* __restrict__ jit, float4* __restrict__ wuser,
                       float4* __restrict__ witem, int last) {
    int j = blockIdx.x * blockDim.x + threadIdx.x;
    if (j >= ptr[NUM_USER]) return;
    float4 s = softmax4(S4[j]);
    float4 p = pscore[j];
    float4 snew = make_float4(s.x + p.x, s.y + p.y, s.z + p.z, s.w + p.w);
    S4[j] = snew;
    if (!last) {
        float n = normu[j];
        float4 q = softmax4(snew);
        float4 w = make_float4(n * q.x, n * q.y, n * q.z, n * q.w);
        wuser[j] = w;
        if (n > 0.0f) witem[jit[j]] = w;   // fire-and-forget scatter, off hot path
    }
}

extern "C" void kernel_launch(void* const* d_in, const int* in_sizes, int n_in,
                              void* d_out, int out_size, void* d_ws, size_t ws_size,
                              hipStream_t stream) {
    const float* user = (const float*)d_in[0];
    const float* item = (const float*)d_in[1];
    const float* S_in = (const float*)d_in[2];
    const int* edge = (const int*)d_in[3];
    const int* row0 = edge;
    const int* col0 = edge + NE;

    float* out = (float*)d_out;
    float* allemb = out;              // NN*DIM floats
    float* Sfinal = out + NN * DIM;   // KF*NE floats

    char* ws = (char*)d_ws;
    size_t off = 0;
    auto carve = [&](size_t bytes) { void* p = ws + off; off += (bytes + 255) & ~(size_t)255; return p; };
    int* cnt = (int*)carve((NN + 1) * sizeof(int));
    int* cntp = (int*)carve((NN + 1) * sizeof(int));
    int* ptr = (int*)carve((NN + 1) * sizeof(int));
    int* pos = (int*)carve((NN + 1) * sizeof(int));
    int* bsum = (int*)carve(256 * sizeof(int));
    int* offs = (int*)carve(256 * sizeof(int));
    int* srcadj = (int*)carve((size_t)(NEPU_MAX + NEPI_MAX) * sizeof(int));
    int* jit = (int*)carve((size_t)NEPU_MAX * sizeof(int));
    int* jpos1 = (int*)carve((size_t)NE * sizeof(int));
    float* dinv = (float*)carve(NN * sizeof(float));
    float* normu = (float*)carve((size_t)NEPU_MAX * sizeof(float));
    float4* Scur4 = (float4*)carve((size_t)NEPU_MAX * sizeof(float4));
    float4* wuser = (float4*)carve((size_t)NEPU_MAX * sizeof(float4));
    float4* witem = (float4*)carve((size_t)NEPI_MAX * sizeof(float4));
    float4* pscore = (float4*)carve((size_t)NEPU_MAX * sizeof(float4));
    unsigned short* egoUA = (unsigned short*)carve((size_t)NUM_USER * DIM * 2);
    unsigned short* egoUB = (unsigned short*)carve((size_t)NUM_USER * DIM * 2);
    unsigned* cmbIA = (unsigned*)carve((size_t)NUM_ITEM * DIM * 4);
    unsigned* cmbIB = (unsigned*)carve((size_t)NUM_ITEM * DIM * 4);

    hipMemsetAsync(cnt, 0, (NN + 1) * sizeof(int), stream);
    hipMemsetAsync(normu, 0, (size_t)NEPU_MAX * sizeof(float), stream);
    hipMemsetAsync(Scur4, 0, (size_t)NEPU_MAX * sizeof(float4), stream);
    hipMemsetAsync(wuser, 0, (size_t)NEPU_MAX * sizeof(float4), stream);
    hipMemsetAsync(witem, 0, (size_t)NEPI_MAX * sizeof(float4), stream);

    k_count<<<(NE + 255) / 256, 256, 0, stream>>>(row0, col0, cnt);
    k_dinv_pad<<<(NN + 255) / 256, 256, 0, stream>>>(cnt, dinv, cntp);
    k_scan1<<<NBLK_SCAN, SCAN_CHUNK, 0, stream>>>(cntp, ptr, bsum);
    k_scan2<<<1, 256, 0, stream>>>(bsum, offs);
    k_scan3<<<(NN + 1 + 255) / 256, 256, 0, stream>>>(ptr, offs);
    hipMemcpyAsync(pos, ptr, (NN + 1) * sizeof(int), hipMemcpyDeviceToDevice, stream);
    k_fill<<<(NE + 255) / 256, 256, 0, stream>>>(row0, col0, pos, ptr, srcadj, jit, jpos1);
    k_pad<<<(NN + 255) / 256, 256, 0, stream>>>(cnt, ptr, srcadj);
    k_w0<<<(NE + 255) / 256, 256, 0, stream>>>(S_in, row0, col0, jpos1, jit, dinv,
                                               Scur4, normu, wuser, witem);
    k_init<<<(NN * 64 + 255) / 256, 256, 0, stream>>>(user, item, egoUA, cmbIA, allemb);

    unsigned short* egoU = egoUA;
    unsigned short* egoUn = egoUB;
    unsigned* cmbI = cmbIA;
    unsigned* cmbIn = cmbIB;
    for (int layer = 0; layer < 2; ++layer) {
        for (int it = 0; it < 2; ++it) {
            int flags = 0;
            if (it == 1) flags |= 1;                   // layer end: allemb += acc
            if (it == 1 && layer == 0) flags |= 4;     // write next ego (+item T)
            k_conv_score<<<(NN * 64 + 255) / 256, 256, 0, stream>>>(
                ptr, srcadj, (const float*)wuser, (const float*)witem,
                (float*)pscore, egoU, cmbI, egoUn, cmbIn, allemb, flags);
            int last = (layer == 1 && it == 1) ? 1 : 0;
            k_supd<<<(NEPU_MAX + 255) / 256, 256, 0, stream>>>(
                ptr, Scur4, pscore, normu, jit, wuser, witem, last);
        }
        unsigned short* t = egoU; egoU = egoUn; egoUn = t;
        unsigned* tc = cmbI; cmbI = cmbIn; cmbIn = tc;
    }
    k_sout<<<(NE + 255) / 256, 256, 0, stream>>>(Scur4, jpos1, Sfinal);
}